// Round 1
// baseline (1719.200 us; speedup 1.0000x reference)
//
#include <hip/hip_runtime.h>
#include <hip/hip_bf16.h>

#define E_ 128
#define NSAMP 2048

typedef __attribute__((ext_vector_type(8))) short short8;
typedef __attribute__((ext_vector_type(4))) float floatx4;

__device__ __forceinline__ ushort f2b(float f) {
    union { __hip_bfloat16 h; ushort u; } cv;
    cv.h = __float2bfloat16(f);
    return cv.u;
}

// -------------------- h = ReLU(ids @ l1W^T + l1b), fp32 --------------------
__global__ void hyper_h(const float* __restrict__ input, const float* __restrict__ l1W,
                        const float* __restrict__ l1b, float* __restrict__ h)
{
    int b = blockIdx.x / 5;
    int o = (blockIdx.x % 5) * 256 + threadIdx.x;
    const float* ids = input + (size_t)b * 192 + 176;
    const float* w = l1W + (size_t)o * 16;
    float a = l1b[o];
#pragma unroll
    for (int i = 0; i < 16; i += 4) {
        float4 wv = *(const float4*)(w + i);
        a += ids[i] * wv.x + ids[i + 1] * wv.y + ids[i + 2] * wv.z + ids[i + 3] * wv.w;
    }
    h[(size_t)b * 1280 + o] = fmaxf(a, 0.f);
}

// -------------------- xT0[s][b] = input[b][s]  (s < 176), fp32 --------------------
__global__ void x0_t(const float* __restrict__ input, float* __restrict__ xT0)
{
    int idx = blockIdx.x * 256 + threadIdx.x;   // < 176*2048
    int s = idx >> 11, b = idx & 2047;
    xT0[idx] = input[(size_t)b * 192 + s];
}

// -------------------- fp32 -> bf16 convert --------------------
__global__ void cvt_bf16(const float* __restrict__ src, ushort* __restrict__ dst, int n)
{
    int i = (blockIdx.x * 256 + threadIdx.x) * 8;
    if (i >= n) return;
    float4 a = *(const float4*)(src + i);
    float4 b = *(const float4*)(src + i + 4);
    union { ushort o[8]; uint4 v; } u;
    u.o[0] = f2b(a.x); u.o[1] = f2b(a.y); u.o[2] = f2b(a.z); u.o[3] = f2b(a.w);
    u.o[4] = f2b(b.x); u.o[5] = f2b(b.y); u.o[6] = f2b(b.z); u.o[7] = f2b(b.w);
    *(uint4*)(dst + i) = u.v;
}

// -------------------- bias[b][m] = bb[m] + sum_e h_ib*bW + sum_s x*wb --------------------
template<int MT>
__global__ void bias_k(const float* __restrict__ h, const float* __restrict__ xT,
                       const float* __restrict__ bW, const float* __restrict__ bb,
                       const float* __restrict__ wb, float* __restrict__ bias,
                       int S, int ib)
{
    int m = threadIdx.x % MT;
    int bsub = threadIdx.x / MT;
    int b = blockIdx.x * (256 / MT) + bsub;
    const float* hb = h + (size_t)b * 1280 + (size_t)ib * E_;
    float a = bb[m];
    for (int e = 0; e < E_; e += 4) {
        float4 w = *(const float4*)(bW + (size_t)m * E_ + e);
        a += hb[e] * w.x + hb[e + 1] * w.y + hb[e + 2] * w.z + hb[e + 3] * w.w;
    }
    for (int s = 0; s < S; ++s)
        a += xT[(size_t)s * NSAMP + b] * wb[(size_t)s * MT + m];
    bias[(size_t)b * MT + m] = a;
}

// -------------------- main fused GEMM: partial[ks][b][m] = sum_{s in split} sum_e (x*h)*wW --------------------
// A[b][e] = x[b,s]*h[b,e] generated in-kernel (h cached in regs as fp32, single bf16 rounding).
// B = wWb viewed [S][M][E]: rows are already 8-consecutive-e => MFMA B-frag layout directly.
template<int BM, int BN, int WROWS, int WCOLS>
__global__ __launch_bounds__(256, 2) void gemm_k(
    const ushort* __restrict__ wWb, const float* __restrict__ h,
    const float* __restrict__ xT, float* __restrict__ partial,
    int S, int M, int iw, int split_s, int btiles, int ntiles)
{
    constexpr int SM = BM / WROWS / 16;
    constexpr int SN = BN / WCOLS / 16;
    constexpr int ASLOTS = BM * 8 / 256;   // per-phase A 16B-slots per thread
    constexpr int LDA = 72;                // 64 + 8 bf16 pad (16B) -> conflict-free frags

    __shared__ ushort As[BM][LDA];
    __shared__ ushort Bs[BN][LDA];

    const int tid = threadIdx.x;
    const int bt = blockIdx.x % btiles;
    const int nt = (blockIdx.x / btiles) % ntiles;
    const int ks = blockIdx.x / (btiles * ntiles);
    const int b0 = bt * BM;
    const int m0 = nt * BN;
    const int s0 = ks * split_s;
    const int s1 = min(s0 + split_s, S);

    const int lane = tid & 63;
    const int wave = tid >> 6;
    const int quad = lane >> 4;
    const int lr = lane & 15;
    const int wm0 = (wave / WCOLS) * (BM / WROWS);
    const int wn0 = (wave % WCOLS) * (BN / WCOLS);

    const int tb = tid >> 3;    // A-row group base (0..31)
    const int teg = tid & 7;    // e-group within 64-half

    // preload this block's h chunk into registers (fp32, both 64-halves)
    float hreg[ASLOTS][2][8];
#pragma unroll
    for (int k2 = 0; k2 < ASLOTS; ++k2) {
        int b = tb + 32 * k2;
#pragma unroll
        for (int p = 0; p < 2; ++p) {
            const float* src = h + (size_t)(b0 + b) * 1280 + (size_t)iw * E_ + p * 64 + teg * 8;
            float4 v0 = *(const float4*)(src);
            float4 v1 = *(const float4*)(src + 4);
            hreg[k2][p][0] = v0.x; hreg[k2][p][1] = v0.y; hreg[k2][p][2] = v0.z; hreg[k2][p][3] = v0.w;
            hreg[k2][p][4] = v1.x; hreg[k2][p][5] = v1.y; hreg[k2][p][6] = v1.z; hreg[k2][p][7] = v1.w;
        }
    }

    floatx4 acc[SM][SN];
#pragma unroll
    for (int i = 0; i < SM; ++i)
#pragma unroll
        for (int j = 0; j < SN; ++j)
            acc[i][j] = (floatx4){0.f, 0.f, 0.f, 0.f};

    for (int s = s0; s < s1; ++s) {
        float xv[ASLOTS];
#pragma unroll
        for (int k2 = 0; k2 < ASLOTS; ++k2)
            xv[k2] = xT[(size_t)s * NSAMP + b0 + tb + 32 * k2];

#pragma unroll
        for (int p = 0; p < 2; ++p) {
            // stage A = x*h (fp32 product, one bf16 rounding)
#pragma unroll
            for (int k2 = 0; k2 < ASLOTS; ++k2) {
                union { ushort o[8]; uint4 v; } u;
#pragma unroll
                for (int j = 0; j < 8; ++j) u.o[j] = f2b(xv[k2] * hreg[k2][p][j]);
                *(uint4*)&As[tb + 32 * k2][teg * 8] = u.v;
            }
            // stage B: contiguous bf16 rows of wWb
#pragma unroll
            for (int slot = tid; slot < BN * 8; slot += 256) {
                int m = slot >> 3, eg2 = slot & 7;
                *(uint4*)&Bs[m][eg2 * 8] =
                    *(const uint4*)(wWb + ((size_t)s * M + m0 + m) * E_ + p * 64 + eg2 * 8);
            }
            __syncthreads();
#pragma unroll
            for (int kk = 0; kk < 2; ++kk) {
                short8 af[SM], bfr[SN];
#pragma unroll
                for (int i = 0; i < SM; ++i)
                    af[i] = *(const short8*)&As[wm0 + i * 16 + lr][kk * 32 + quad * 8];
#pragma unroll
                for (int j = 0; j < SN; ++j)
                    bfr[j] = *(const short8*)&Bs[wn0 + j * 16 + lr][kk * 32 + quad * 8];
#pragma unroll
                for (int i = 0; i < SM; ++i)
#pragma unroll
                    for (int j = 0; j < SN; ++j)
                        acc[i][j] = __builtin_amdgcn_mfma_f32_16x16x32_bf16(af[i], bfr[j], acc[i][j], 0, 0, 0);
            }
            __syncthreads();
        }
    }

    // epilogue: C/D layout col=lane&15, row=quad*4+r  (m89-verified)
    float* dst = partial + (size_t)ks * NSAMP * M;
#pragma unroll
    for (int i = 0; i < SM; ++i)
#pragma unroll
        for (int j = 0; j < SN; ++j)
#pragma unroll
            for (int r = 0; r < 4; ++r) {
                int row = wm0 + i * 16 + quad * 4 + r;
                int col = wn0 + j * 16 + lr;
                dst[(size_t)(b0 + row) * M + m0 + col] = acc[i][j][r];
            }
}

// -------------------- reduce partials + bias (+ReLU), emit xT fp32 for next layer --------------------
__global__ void reduce_mid(const float* __restrict__ partial, const float* __restrict__ bias,
                           float* __restrict__ xTn, int KS, int relu)
{
    __shared__ float t[32][257];
    int b0 = blockIdx.x * 32;
    for (int idx = threadIdx.x; idx < 32 * 256; idx += 256) {
        int m = idx & 255, bs = idx >> 8;
        size_t off = (size_t)(b0 + bs) * 256 + m;
        float a = bias[off];
        for (int k = 0; k < KS; ++k) a += partial[(size_t)k * NSAMP * 256 + off];
        if (relu) a = fmaxf(a, 0.f);
        t[bs][m] = a;
    }
    __syncthreads();
    for (int idx = threadIdx.x; idx < 32 * 256; idx += 256) {
        int bs = idx & 31, m = idx >> 5;
        xTn[(size_t)m * NSAMP + b0 + bs] = t[bs][m];
    }
}

// -------------------- final layer reduce -> d_out (fp32, ReLU) --------------------
__global__ void reduce_out(const float* __restrict__ partial, const float* __restrict__ bias,
                           float* __restrict__ out, int KS)
{
    int idx = blockIdx.x * 256 + threadIdx.x;   // < 2048*16
    float a = bias[idx];
    for (int k = 0; k < KS; ++k) a += partial[(size_t)k * (NSAMP * 16) + idx];
    out[idx] = fmaxf(a, 0.f);
}

extern "C" void kernel_launch(void* const* d_in, const int* in_sizes, int n_in,
                              void* d_out, int out_size, void* d_ws, size_t ws_size,
                              hipStream_t stream)
{
    const float* input = (const float*)d_in[0];
    const float* l1W   = (const float*)d_in[1];
    const float* l1b   = (const float*)d_in[2];

    char* ws = (char*)d_ws;
    // layout (bytes): wWb 16.78M | h 10.49M | xT0 2M | xT1 2M | bias 2M | partial 33.55M = 64MB
    ushort* wWb = (ushort*)(ws + 0);
    float* h    = (float*)(ws + 16777216);
    float* xT0  = (float*)(ws + 27262976);
    float* xT1  = (float*)(ws + 29360128);
    float* bias = (float*)(ws + 31457280);
    float* part = (float*)(ws + 33554432);

    hipLaunchKernelGGL(hyper_h, dim3(2048 * 5), dim3(256), 0, stream, input, l1W, l1b, h);
    hipLaunchKernelGGL(x0_t, dim3(176 * 2048 / 256), dim3(256), 0, stream, input, xT0);

    const int S_[5] = {176, 256, 256, 256, 256};
    const int M_[5] = {256, 256, 256, 256, 16};
    float* xt[2] = {xT0, xT1};

    for (int i = 0; i < 5; ++i) {
        const float* wW = (const float*)d_in[3 + 4 * i];
        const float* wb = (const float*)d_in[4 + 4 * i];
        const float* bW = (const float*)d_in[5 + 4 * i];
        const float* bb = (const float*)d_in[6 + 4 * i];
        float* xin = xt[i & 1];
        int n = S_[i] * M_[i] * E_;
        hipLaunchKernelGGL(cvt_bf16, dim3(n / 2048), dim3(256), 0, stream, wW, wWb, n);

        if (M_[i] == 256) {
            hipLaunchKernelGGL(bias_k<256>, dim3(2048), dim3(256), 0, stream,
                               h, xin, bW, bb, wb, bias, S_[i], 2 * i + 1);
            const int btiles = 16, ntiles = 2, ksplit = 16;
            hipLaunchKernelGGL((gemm_k<128, 128, 2, 2>), dim3(btiles * ntiles * ksplit), dim3(256), 0, stream,
                               wWb, h, xin, part, S_[i], 256, 2 * i,
                               (S_[i] + ksplit - 1) / ksplit, btiles, ntiles);
            hipLaunchKernelGGL(reduce_mid, dim3(64), dim3(256), 0, stream,
                               part, bias, xt[(i + 1) & 1], ksplit, (i < 3) ? 1 : 0);
        } else {
            hipLaunchKernelGGL(bias_k<16>, dim3(128), dim3(256), 0, stream,
                               h, xin, bW, bb, wb, bias, S_[i], 2 * i + 1);
            const int btiles = 8, ntiles = 1, ksplit = 32;
            hipLaunchKernelGGL((gemm_k<256, 16, 4, 1>), dim3(btiles * ntiles * ksplit), dim3(256), 0, stream,
                               wWb, h, xin, part, S_[i], 16, 2 * i, 8, btiles, ntiles);
            hipLaunchKernelGGL(reduce_out, dim3(128), dim3(256), 0, stream,
                               part, bias, (float*)d_out, ksplit);
        }
    }
}

// Round 2
// 1068.068 us; speedup vs baseline: 1.6096x; 1.6096x over previous
//
#include <hip/hip_runtime.h>
#include <hip/hip_bf16.h>

#define E_ 128
#define NSAMP 2048

typedef __attribute__((ext_vector_type(8))) short short8;
typedef __attribute__((ext_vector_type(4))) float floatx4;

__device__ __forceinline__ ushort f2b(float f) {
    union { __hip_bfloat16 h; ushort u; } cv;
    cv.h = __float2bfloat16(f);
    return cv.u;
}

// -------------------- h = ReLU(ids @ l1W^T + l1b), fp32 --------------------
__global__ void hyper_h(const float* __restrict__ input, const float* __restrict__ l1W,
                        const float* __restrict__ l1b, float* __restrict__ h)
{
    int b = blockIdx.x / 5;
    int o = (blockIdx.x % 5) * 256 + threadIdx.x;
    const float* ids = input + (size_t)b * 192 + 176;
    const float* w = l1W + (size_t)o * 16;
    float a = l1b[o];
#pragma unroll
    for (int i = 0; i < 16; i += 4) {
        float4 wv = *(const float4*)(w + i);
        a += ids[i] * wv.x + ids[i + 1] * wv.y + ids[i + 2] * wv.z + ids[i + 3] * wv.w;
    }
    h[(size_t)b * 1280 + o] = fmaxf(a, 0.f);
}

// -------------------- xT0[s][b] = input[b][s]  (s < 176), fp32 --------------------
__global__ void x0_t(const float* __restrict__ input, float* __restrict__ xT0)
{
    int idx = blockIdx.x * 256 + threadIdx.x;   // < 176*2048
    int s = idx >> 11, b = idx & 2047;
    xT0[idx] = input[(size_t)b * 192 + s];
}

// -------------------- fp32 -> bf16 convert (wW bulk) --------------------
__global__ void cvt_bf16(const float* __restrict__ src, ushort* __restrict__ dst, int n)
{
    int i = (blockIdx.x * 256 + threadIdx.x) * 8;
    if (i >= n) return;
    float4 a = *(const float4*)(src + i);
    float4 b = *(const float4*)(src + i + 4);
    union { ushort o[8]; uint4 v; } u;
    u.o[0] = f2b(a.x); u.o[1] = f2b(a.y); u.o[2] = f2b(a.z); u.o[3] = f2b(a.w);
    u.o[4] = f2b(b.x); u.o[5] = f2b(b.y); u.o[6] = f2b(b.z); u.o[7] = f2b(b.w);
    *(uint4*)(dst + i) = u.v;
}

// -------------------- build 3 virtual B-slices: [S]=bW rows, [S+1..S+2]=wb^T chunks --------
__global__ void cvt_bias(const float* __restrict__ bW, const float* __restrict__ wb,
                         ushort* __restrict__ dst, int S, int M)
{
    int idx = blockIdx.x * 256 + threadIdx.x;   // < 3*M*E_
    int slice = idx / (M * E_);
    int rem = idx - slice * (M * E_);
    int m = rem / E_, e = rem - m * E_;
    ushort v;
    if (slice == 0) {
        v = f2b(bW[(size_t)m * E_ + e]);
    } else {
        int s = (slice - 1) * 128 + e;
        v = (s < S) ? f2b(wb[(size_t)s * M + m]) : (ushort)0;
    }
    dst[(size_t)(S + slice) * M * E_ + rem] = v;
}

// -------------------- main fused GEMM over S+3 slices --------------------
// slice s<S     : A[b][e] = x[b,s]*h[b, iw-chunk, e]   (generated from regs)
// slice s==S    : A[b][e] = h[b, (iw+1)-chunk, e]      (bias bW term)
// slice s>S     : A[b][e] = x[b, (s-S-1)*128+e]        (bias wb term, gathered from xT)
// B = wWb viewed [S+3][M][E]; rows already contiguous-e => direct MFMA B-frag.
template<int BM, int BN, int WROWS, int WCOLS>
__global__ __launch_bounds__(256, 2) void gemm_k(
    const ushort* __restrict__ wWb, const float* __restrict__ h,
    const float* __restrict__ xT, float* __restrict__ partial,
    int S, int M, int iw, int split_s, int btiles, int ntiles)
{
    constexpr int SM = BM / WROWS / 16;
    constexpr int SN = BN / WCOLS / 16;
    constexpr int ASLOTS = BM * 8 / 256;   // per-phase 16B A-slots per thread
    constexpr int LDA = 72;                // 64 + 8 bf16 pad -> conflict-free frags

    __shared__ ushort As[BM][LDA];
    __shared__ ushort Bs[BN][LDA];

    const int tid = threadIdx.x;
    const int bt = blockIdx.x % btiles;
    const int nt = (blockIdx.x / btiles) % ntiles;
    const int ks = blockIdx.x / (btiles * ntiles);
    const int b0 = bt * BM;
    const int m0 = nt * BN;
    const int total_s = S + 3;
    const int s0 = ks * split_s;
    const int s1 = min(s0 + split_s, total_s);

    const int lane = tid & 63;
    const int wave = tid >> 6;
    const int quad = lane >> 4;
    const int lr = lane & 15;
    const int wm0 = (wave / WCOLS) * (BM / WROWS);
    const int wn0 = (wave % WCOLS) * (BN / WCOLS);

    const int tb = tid >> 3;    // A-row group base (0..31)
    const int teg = tid & 7;    // e-group within 64-half

    // preload this block's h chunk (iw) into registers, fp32
    float hreg[ASLOTS][2][8];
#pragma unroll
    for (int k2 = 0; k2 < ASLOTS; ++k2) {
        int b = tb + 32 * k2;
#pragma unroll
        for (int p = 0; p < 2; ++p) {
            const float* src = h + (size_t)(b0 + b) * 1280 + (size_t)iw * E_ + p * 64 + teg * 8;
            float4 v0 = *(const float4*)(src);
            float4 v1 = *(const float4*)(src + 4);
            hreg[k2][p][0] = v0.x; hreg[k2][p][1] = v0.y; hreg[k2][p][2] = v0.z; hreg[k2][p][3] = v0.w;
            hreg[k2][p][4] = v1.x; hreg[k2][p][5] = v1.y; hreg[k2][p][6] = v1.z; hreg[k2][p][7] = v1.w;
        }
    }

    floatx4 acc[SM][SN];
#pragma unroll
    for (int i = 0; i < SM; ++i)
#pragma unroll
        for (int j = 0; j < SN; ++j)
            acc[i][j] = (floatx4){0.f, 0.f, 0.f, 0.f};

    for (int s = s0; s < s1; ++s) {
        float xv[ASLOTS];
        if (s < S) {
#pragma unroll
            for (int k2 = 0; k2 < ASLOTS; ++k2)
                xv[k2] = xT[(size_t)s * NSAMP + b0 + tb + 32 * k2];
        }

#pragma unroll
        for (int p = 0; p < 2; ++p) {
            if (s < S) {
                // A = x*h (fp32 product, one bf16 rounding)
#pragma unroll
                for (int k2 = 0; k2 < ASLOTS; ++k2) {
                    union { ushort o[8]; uint4 v; } u;
#pragma unroll
                    for (int j = 0; j < 8; ++j) u.o[j] = f2b(xv[k2] * hreg[k2][p][j]);
                    *(uint4*)&As[tb + 32 * k2][teg * 8] = u.v;
                }
            } else if (s == S) {
                // A = h_(iw+1) chunk (bias bW term)
#pragma unroll
                for (int k2 = 0; k2 < ASLOTS; ++k2) {
                    const float* src = h + (size_t)(b0 + tb + 32 * k2) * 1280
                                         + (size_t)(iw + 1) * E_ + p * 64 + teg * 8;
                    float4 v0 = *(const float4*)(src);
                    float4 v1 = *(const float4*)(src + 4);
                    union { ushort o[8]; uint4 v; } u;
                    u.o[0] = f2b(v0.x); u.o[1] = f2b(v0.y); u.o[2] = f2b(v0.z); u.o[3] = f2b(v0.w);
                    u.o[4] = f2b(v1.x); u.o[5] = f2b(v1.y); u.o[6] = f2b(v1.z); u.o[7] = f2b(v1.w);
                    *(uint4*)&As[tb + 32 * k2][teg * 8] = u.v;
                }
            } else {
                // A = raw x gathered from xT (bias wb term)
                int j0 = (s - S - 1) * 128 + p * 64 + teg * 8;
#pragma unroll
                for (int k2 = 0; k2 < ASLOTS; ++k2) {
                    int b = b0 + tb + 32 * k2;
                    union { ushort o[8]; uint4 v; } u;
#pragma unroll
                    for (int jj = 0; jj < 8; ++jj) {
                        int sp = j0 + jj;
                        u.o[jj] = (sp < S) ? f2b(xT[(size_t)sp * NSAMP + b]) : (ushort)0;
                    }
                    *(uint4*)&As[tb + 32 * k2][teg * 8] = u.v;
                }
            }
            // stage B: contiguous bf16 rows of wWb (slices 0..S+2)
#pragma unroll
            for (int slot = tid; slot < BN * 8; slot += 256) {
                int m = slot >> 3, eg2 = slot & 7;
                *(uint4*)&Bs[m][eg2 * 8] =
                    *(const uint4*)(wWb + ((size_t)s * M + m0 + m) * E_ + p * 64 + eg2 * 8);
            }
            __syncthreads();
#pragma unroll
            for (int kk = 0; kk < 2; ++kk) {
                short8 af[SM], bfr[SN];
#pragma unroll
                for (int i = 0; i < SM; ++i)
                    af[i] = *(const short8*)&As[wm0 + i * 16 + lr][kk * 32 + quad * 8];
#pragma unroll
                for (int j = 0; j < SN; ++j)
                    bfr[j] = *(const short8*)&Bs[wn0 + j * 16 + lr][kk * 32 + quad * 8];
#pragma unroll
                for (int i = 0; i < SM; ++i)
#pragma unroll
                    for (int j = 0; j < SN; ++j)
                        acc[i][j] = __builtin_amdgcn_mfma_f32_16x16x32_bf16(af[i], bfr[j], acc[i][j], 0, 0, 0);
            }
            __syncthreads();
        }
    }

    // epilogue: C/D layout col=lane&15, row=quad*4+r  (m89-verified)
    float* dst = partial + (size_t)ks * NSAMP * M;
#pragma unroll
    for (int i = 0; i < SM; ++i)
#pragma unroll
        for (int j = 0; j < SN; ++j)
#pragma unroll
            for (int r = 0; r < 4; ++r) {
                int row = wm0 + i * 16 + quad * 4 + r;
                int col = wn0 + j * 16 + lr;
                dst[(size_t)(b0 + row) * M + m0 + col] = acc[i][j][r];
            }
}

// -------------------- reduce partials + bb (+ReLU), emit xT fp32 for next layer --------------------
__global__ void reduce_mid(const float* __restrict__ partial, const float* __restrict__ bb,
                           float* __restrict__ xTn, int KS, int relu)
{
    __shared__ float t[32][257];
    int b0 = blockIdx.x * 32;
    for (int idx = threadIdx.x; idx < 32 * 256; idx += 256) {
        int m = idx & 255, bs = idx >> 8;
        size_t off = (size_t)(b0 + bs) * 256 + m;
        float a = bb[m];
        for (int k = 0; k < KS; ++k) a += partial[(size_t)k * NSAMP * 256 + off];
        if (relu) a = fmaxf(a, 0.f);
        t[bs][m] = a;
    }
    __syncthreads();
    for (int idx = threadIdx.x; idx < 32 * 256; idx += 256) {
        int bs = idx & 31, m = idx >> 5;
        xTn[(size_t)m * NSAMP + b0 + bs] = t[bs][m];
    }
}

// -------------------- final layer reduce -> d_out (fp32, ReLU) --------------------
__global__ void reduce_out(const float* __restrict__ partial, const float* __restrict__ bb,
                           float* __restrict__ out, int KS)
{
    int idx = blockIdx.x * 256 + threadIdx.x;   // < 2048*16
    float a = bb[idx & 15];
    for (int k = 0; k < KS; ++k) a += partial[(size_t)k * (NSAMP * 16) + idx];
    out[idx] = fmaxf(a, 0.f);
}

extern "C" void kernel_launch(void* const* d_in, const int* in_sizes, int n_in,
                              void* d_out, int out_size, void* d_ws, size_t ws_size,
                              hipStream_t stream)
{
    const float* input = (const float*)d_in[0];
    const float* l1W   = (const float*)d_in[1];
    const float* l1b   = (const float*)d_in[2];

    char* ws = (char*)d_ws;
    // layout (bytes): wWb 16.98M | h 10.49M | xT0 2M | xT1 2M | partial 33.55M = 65.2MB
    ushort* wWb = (ushort*)(ws + 0);
    float* h    = (float*)(ws + 16975872);
    float* xT0  = (float*)(ws + 27461632);
    float* xT1  = (float*)(ws + 29558784);
    float* part = (float*)(ws + 31655936);

    hipLaunchKernelGGL(hyper_h, dim3(2048 * 5), dim3(256), 0, stream, input, l1W, l1b, h);
    hipLaunchKernelGGL(x0_t, dim3(176 * 2048 / 256), dim3(256), 0, stream, input, xT0);

    const int S_[5] = {176, 256, 256, 256, 256};
    const int M_[5] = {256, 256, 256, 256, 16};
    float* xt[2] = {xT0, xT1};

    for (int i = 0; i < 5; ++i) {
        const float* wW = (const float*)d_in[3 + 4 * i];
        const float* wb = (const float*)d_in[4 + 4 * i];
        const float* bW = (const float*)d_in[5 + 4 * i];
        const float* bb = (const float*)d_in[6 + 4 * i];
        float* xin = xt[i & 1];
        int n = S_[i] * M_[i] * E_;
        hipLaunchKernelGGL(cvt_bf16, dim3(n / 2048), dim3(256), 0, stream, wW, wWb, n);
        hipLaunchKernelGGL(cvt_bias, dim3(3 * M_[i] * E_ / 256), dim3(256), 0, stream,
                           bW, wb, wWb, S_[i], M_[i]);

        if (M_[i] == 256) {
            const int btiles = 16, ntiles = 2, ksplit = 16;
            int split_s = (S_[i] + 3 + ksplit - 1) / ksplit;
            hipLaunchKernelGGL((gemm_k<128, 128, 2, 2>), dim3(btiles * ntiles * ksplit), dim3(256), 0, stream,
                               wWb, h, xin, part, S_[i], 256, 2 * i, split_s, btiles, ntiles);
            hipLaunchKernelGGL(reduce_mid, dim3(64), dim3(256), 0, stream,
                               part, bb, xt[(i + 1) & 1], ksplit, (i < 3) ? 1 : 0);
        } else {
            const int btiles = 8, ntiles = 1, ksplit = 32;
            int split_s = (S_[i] + 3 + ksplit - 1) / ksplit;
            hipLaunchKernelGGL((gemm_k<256, 16, 4, 1>), dim3(btiles * ntiles * ksplit), dim3(256), 0, stream,
                               wWb, h, xin, part, S_[i], 16, 2 * i, split_s, btiles, ntiles);
            hipLaunchKernelGGL(reduce_out, dim3(128), dim3(256), 0, stream,
                               part, bb, (float*)d_out, ksplit);
        }
    }
}

// Round 3
// 682.939 us; speedup vs baseline: 2.5174x; 1.5639x over previous
//
#include <hip/hip_runtime.h>
#include <hip/hip_bf16.h>

#define E_ 128
#define NSAMP 2048

typedef __attribute__((ext_vector_type(8))) short short8;
typedef __attribute__((ext_vector_type(4))) float floatx4;

__device__ __forceinline__ ushort f2b(float f) {
    union { __hip_bfloat16 h; ushort u; } cv;
    cv.h = __float2bfloat16(f);
    return cv.u;
}

// -------------------- h = ReLU(ids @ l1W^T + l1b), fp32 --------------------
__global__ void hyper_h(const float* __restrict__ input, const float* __restrict__ l1W,
                        const float* __restrict__ l1b, float* __restrict__ h)
{
    int b = blockIdx.x / 5;
    int o = (blockIdx.x % 5) * 256 + threadIdx.x;
    const float* ids = input + (size_t)b * 192 + 176;
    const float* w = l1W + (size_t)o * 16;
    float a = l1b[o];
#pragma unroll
    for (int i = 0; i < 16; i += 4) {
        float4 wv = *(const float4*)(w + i);
        a += ids[i] * wv.x + ids[i + 1] * wv.y + ids[i + 2] * wv.z + ids[i + 3] * wv.w;
    }
    h[(size_t)b * 1280 + o] = fmaxf(a, 0.f);
}

// -------------------- xT0[s][b] = input[b][s]  (s < 176), fp32 --------------------
__global__ void x0_t(const float* __restrict__ input, float* __restrict__ xT0)
{
    int idx = blockIdx.x * 256 + threadIdx.x;   // < 176*2048
    int s = idx >> 11, b = idx & 2047;
    xT0[idx] = input[(size_t)b * 192 + s];
}

// -------------------- fp32 -> bf16 convert (wW bulk) --------------------
__global__ void cvt_bf16(const float* __restrict__ src, ushort* __restrict__ dst, int n)
{
    int i = (blockIdx.x * 256 + threadIdx.x) * 8;
    if (i >= n) return;
    float4 a = *(const float4*)(src + i);
    float4 b = *(const float4*)(src + i + 4);
    union { ushort o[8]; uint4 v; } u;
    u.o[0] = f2b(a.x); u.o[1] = f2b(a.y); u.o[2] = f2b(a.z); u.o[3] = f2b(a.w);
    u.o[4] = f2b(b.x); u.o[5] = f2b(b.y); u.o[6] = f2b(b.z); u.o[7] = f2b(b.w);
    *(uint4*)(dst + i) = u.v;
}

// -------------------- build 3 virtual B-slices: [S]=bW rows, [S+1..S+2]=wb^T chunks --------
__global__ void cvt_bias(const float* __restrict__ bW, const float* __restrict__ wb,
                         ushort* __restrict__ dst, int S, int M)
{
    int idx = blockIdx.x * 256 + threadIdx.x;   // < 3*M*E_
    int slice = idx / (M * E_);
    int rem = idx - slice * (M * E_);
    int m = rem / E_, e = rem - m * E_;
    ushort v;
    if (slice == 0) {
        v = f2b(bW[(size_t)m * E_ + e]);
    } else {
        int s = (slice - 1) * 128 + e;
        v = (s < S) ? f2b(wb[(size_t)s * M + m]) : (ushort)0;
    }
    dst[(size_t)(S + slice) * M * E_ + rem] = v;
}

// -------------------- main fused GEMM over S+3 slices --------------------
// slice s<S     : A[b][e] = x[b,s]*h[b, iw-chunk, e]   (generated from regs)
// slice s==S    : A[b][e] = h[b, (iw+1)-chunk, e]      (bias bW term)
// slice s>S     : A[b][e] = x[b, (s-S-1)*128+e]        (bias wb term, gathered from xT)
// B = wWb viewed [S+3][M][E]; rows already contiguous-e => direct MFMA B-frag.
template<int BM, int BN, int WROWS, int WCOLS>
__global__ __launch_bounds__(256, 2) void gemm_k(
    const ushort* __restrict__ wWb, const float* __restrict__ h,
    const float* __restrict__ xT, float* __restrict__ partial,
    int S, int M, int iw, int ksplit, int btiles, int ntiles)
{
    constexpr int SM = BM / WROWS / 16;
    constexpr int SN = BN / WCOLS / 16;
    constexpr int ASLOTS = BM * 8 / 256;   // per-phase 16B A-slots per thread
    constexpr int LDA = 72;                // 64 + 8 bf16 pad -> conflict-free frags

    __shared__ ushort As[BM][LDA];
    __shared__ ushort Bs[BN][LDA];

    const int tid = threadIdx.x;
    const int bt = blockIdx.x % btiles;
    const int nt = (blockIdx.x / btiles) % ntiles;
    const int ks = blockIdx.x / (btiles * ntiles);
    const int b0 = bt * BM;
    const int m0 = nt * BN;
    const int total_s = S + 3;
    // balanced k-split: first `rem` blocks get base+1 slices
    const int base = total_s / ksplit;
    const int rem = total_s - base * ksplit;
    const int s0 = ks * base + min(ks, rem);
    const int s1 = s0 + base + (ks < rem ? 1 : 0);

    const int lane = tid & 63;
    const int wave = tid >> 6;
    const int quad = lane >> 4;
    const int lr = lane & 15;
    const int wm0 = (wave / WCOLS) * (BM / WROWS);
    const int wn0 = (wave % WCOLS) * (BN / WCOLS);

    const int tb = tid >> 3;    // A-row group base (0..31)
    const int teg = tid & 7;    // e-group within 64-half

    // preload this block's h chunk (iw) into registers, fp32
    float hreg[ASLOTS][2][8];
#pragma unroll
    for (int k2 = 0; k2 < ASLOTS; ++k2) {
        int b = tb + 32 * k2;
#pragma unroll
        for (int p = 0; p < 2; ++p) {
            const float* src = h + (size_t)(b0 + b) * 1280 + (size_t)iw * E_ + p * 64 + teg * 8;
            float4 v0 = *(const float4*)(src);
            float4 v1 = *(const float4*)(src + 4);
            hreg[k2][p][0] = v0.x; hreg[k2][p][1] = v0.y; hreg[k2][p][2] = v0.z; hreg[k2][p][3] = v0.w;
            hreg[k2][p][4] = v1.x; hreg[k2][p][5] = v1.y; hreg[k2][p][6] = v1.z; hreg[k2][p][7] = v1.w;
        }
    }

    floatx4 acc[SM][SN];
#pragma unroll
    for (int i = 0; i < SM; ++i)
#pragma unroll
        for (int j = 0; j < SN; ++j)
            acc[i][j] = (floatx4){0.f, 0.f, 0.f, 0.f};

    for (int s = s0; s < s1; ++s) {
        float xv[ASLOTS];
        if (s < S) {
#pragma unroll
            for (int k2 = 0; k2 < ASLOTS; ++k2)
                xv[k2] = xT[(size_t)s * NSAMP + b0 + tb + 32 * k2];
        }

#pragma unroll
        for (int p = 0; p < 2; ++p) {
            if (s < S) {
                // A = x*h (fp32 product, one bf16 rounding)
#pragma unroll
                for (int k2 = 0; k2 < ASLOTS; ++k2) {
                    union { ushort o[8]; uint4 v; } u;
#pragma unroll
                    for (int j = 0; j < 8; ++j) u.o[j] = f2b(xv[k2] * hreg[k2][p][j]);
                    *(uint4*)&As[tb + 32 * k2][teg * 8] = u.v;
                }
            } else if (s == S) {
                // A = h_(iw+1) chunk (bias bW term)
#pragma unroll
                for (int k2 = 0; k2 < ASLOTS; ++k2) {
                    const float* src = h + (size_t)(b0 + tb + 32 * k2) * 1280
                                         + (size_t)(iw + 1) * E_ + p * 64 + teg * 8;
                    float4 v0 = *(const float4*)(src);
                    float4 v1 = *(const float4*)(src + 4);
                    union { ushort o[8]; uint4 v; } u;
                    u.o[0] = f2b(v0.x); u.o[1] = f2b(v0.y); u.o[2] = f2b(v0.z); u.o[3] = f2b(v0.w);
                    u.o[4] = f2b(v1.x); u.o[5] = f2b(v1.y); u.o[6] = f2b(v1.z); u.o[7] = f2b(v1.w);
                    *(uint4*)&As[tb + 32 * k2][teg * 8] = u.v;
                }
            } else {
                // A = raw x gathered from xT (bias wb term)
                int j0 = (s - S - 1) * 128 + p * 64 + teg * 8;
#pragma unroll
                for (int k2 = 0; k2 < ASLOTS; ++k2) {
                    int b = b0 + tb + 32 * k2;
                    union { ushort o[8]; uint4 v; } u;
#pragma unroll
                    for (int jj = 0; jj < 8; ++jj) {
                        int sp = j0 + jj;
                        u.o[jj] = (sp < S) ? f2b(xT[(size_t)sp * NSAMP + b]) : (ushort)0;
                    }
                    *(uint4*)&As[tb + 32 * k2][teg * 8] = u.v;
                }
            }
            // stage B: contiguous bf16 rows of wWb (slices 0..S+2)
#pragma unroll
            for (int slot = tid; slot < BN * 8; slot += 256) {
                int m = slot >> 3, eg2 = slot & 7;
                *(uint4*)&Bs[m][eg2 * 8] =
                    *(const uint4*)(wWb + ((size_t)s * M + m0 + m) * E_ + p * 64 + eg2 * 8);
            }
            __syncthreads();
#pragma unroll
            for (int kk = 0; kk < 2; ++kk) {
                short8 af[SM], bfr[SN];
#pragma unroll
                for (int i = 0; i < SM; ++i)
                    af[i] = *(const short8*)&As[wm0 + i * 16 + lr][kk * 32 + quad * 8];
#pragma unroll
                for (int j = 0; j < SN; ++j)
                    bfr[j] = *(const short8*)&Bs[wn0 + j * 16 + lr][kk * 32 + quad * 8];
#pragma unroll
                for (int i = 0; i < SM; ++i)
#pragma unroll
                    for (int j = 0; j < SN; ++j)
                        acc[i][j] = __builtin_amdgcn_mfma_f32_16x16x32_bf16(af[i], bfr[j], acc[i][j], 0, 0, 0);
            }
            __syncthreads();
        }
    }

    // epilogue: C/D layout col=lane&15, row=quad*4+r  (m89-verified)
    float* dst = partial + (size_t)ks * NSAMP * M;
#pragma unroll
    for (int i = 0; i < SM; ++i)
#pragma unroll
        for (int j = 0; j < SN; ++j)
#pragma unroll
            for (int r = 0; r < 4; ++r) {
                int row = wm0 + i * 16 + quad * 4 + r;
                int col = wn0 + j * 16 + lr;
                dst[(size_t)(b0 + row) * M + m0 + col] = acc[i][j][r];
            }
}

// -------------------- reduce partials + bb (+ReLU), emit xT fp32 for next layer --------------
// 32x32 (b x m) tile per block, grid 512; k-loop unrolled x4 into independent accumulators.
__global__ void reduce_mid(const float* __restrict__ partial, const float* __restrict__ bb,
                           float* __restrict__ xTn, int KS, int relu)
{
    __shared__ float t[32][33];
    const int b0 = (blockIdx.x >> 3) * 32;
    const int m0 = (blockIdx.x & 7) * 32;
    const int mo = threadIdx.x & 31;
    const int bs0 = threadIdx.x >> 5;   // 0..7
    const float bv = bb[m0 + mo];
#pragma unroll
    for (int r = 0; r < 4; ++r) {
        const int bs = bs0 + 8 * r;
        const size_t off = (size_t)(b0 + bs) * 256 + m0 + mo;
        float a0 = 0.f, a1 = 0.f, a2 = 0.f, a3 = 0.f;
#pragma unroll
        for (int k = 0; k < 16; k += 4) {
            a0 += partial[(size_t)(k + 0) * (NSAMP * 256) + off];
            a1 += partial[(size_t)(k + 1) * (NSAMP * 256) + off];
            a2 += partial[(size_t)(k + 2) * (NSAMP * 256) + off];
            a3 += partial[(size_t)(k + 3) * (NSAMP * 256) + off];
        }
        float a = (a0 + a1) + (a2 + a3) + bv;
        if (relu) a = fmaxf(a, 0.f);
        t[bs][mo] = a;
    }
    __syncthreads();
    const int bo = threadIdx.x & 31;
    const int ms0 = threadIdx.x >> 5;
#pragma unroll
    for (int r = 0; r < 4; ++r) {
        const int ms = ms0 + 8 * r;
        xTn[(size_t)(m0 + ms) * NSAMP + b0 + bo] = t[bo][ms];
    }
}

// -------------------- final layer reduce -> d_out (fp32, ReLU) --------------------
__global__ void reduce_out(const float* __restrict__ partial, const float* __restrict__ bb,
                           float* __restrict__ out, int KS)
{
    int idx = blockIdx.x * 256 + threadIdx.x;   // < 2048*16
    float a0 = 0.f, a1 = 0.f, a2 = 0.f, a3 = 0.f;
#pragma unroll
    for (int k = 0; k < 32; k += 4) {
        a0 += partial[(size_t)(k + 0) * (NSAMP * 16) + idx];
        a1 += partial[(size_t)(k + 1) * (NSAMP * 16) + idx];
        a2 += partial[(size_t)(k + 2) * (NSAMP * 16) + idx];
        a3 += partial[(size_t)(k + 3) * (NSAMP * 16) + idx];
    }
    out[idx] = fmaxf((a0 + a1) + (a2 + a3) + bb[idx & 15], 0.f);
}

extern "C" void kernel_launch(void* const* d_in, const int* in_sizes, int n_in,
                              void* d_out, int out_size, void* d_ws, size_t ws_size,
                              hipStream_t stream)
{
    const float* input = (const float*)d_in[0];
    const float* l1W   = (const float*)d_in[1];
    const float* l1b   = (const float*)d_in[2];

    char* ws = (char*)d_ws;
    // layout (bytes): wWb 16.98M | h 10.49M | xT0 2M | xT1 2M | partial 33.55M = 65.2MB
    ushort* wWb = (ushort*)(ws + 0);
    float* h    = (float*)(ws + 16975872);
    float* xT0  = (float*)(ws + 27461632);
    float* xT1  = (float*)(ws + 29558784);
    float* part = (float*)(ws + 31655936);

    hipLaunchKernelGGL(hyper_h, dim3(2048 * 5), dim3(256), 0, stream, input, l1W, l1b, h);
    hipLaunchKernelGGL(x0_t, dim3(176 * 2048 / 256), dim3(256), 0, stream, input, xT0);

    const int S_[5] = {176, 256, 256, 256, 256};
    const int M_[5] = {256, 256, 256, 256, 16};
    float* xt[2] = {xT0, xT1};

    for (int i = 0; i < 5; ++i) {
        const float* wW = (const float*)d_in[3 + 4 * i];
        const float* wb = (const float*)d_in[4 + 4 * i];
        const float* bW = (const float*)d_in[5 + 4 * i];
        const float* bb = (const float*)d_in[6 + 4 * i];
        float* xin = xt[i & 1];
        int n = S_[i] * M_[i] * E_;
        hipLaunchKernelGGL(cvt_bf16, dim3(n / 2048), dim3(256), 0, stream, wW, wWb, n);
        hipLaunchKernelGGL(cvt_bias, dim3(3 * M_[i] * E_ / 256), dim3(256), 0, stream,
                           bW, wb, wWb, S_[i], M_[i]);

        if (M_[i] == 256) {
            const int btiles = 16, ntiles = 2, ksplit = 16;
            hipLaunchKernelGGL((gemm_k<128, 128, 2, 2>), dim3(btiles * ntiles * ksplit), dim3(256), 0, stream,
                               wWb, h, xin, part, S_[i], 256, 2 * i, ksplit, btiles, ntiles);
            hipLaunchKernelGGL(reduce_mid, dim3(512), dim3(256), 0, stream,
                               part, bb, xt[(i + 1) & 1], ksplit, (i < 3) ? 1 : 0);
        } else {
            const int btiles = 8, ntiles = 1, ksplit = 32;
            hipLaunchKernelGGL((gemm_k<256, 16, 4, 1>), dim3(btiles * ntiles * ksplit), dim3(256), 0, stream,
                               wWb, h, xin, part, S_[i], 16, 2 * i, ksplit, btiles, ntiles);
            hipLaunchKernelGGL(reduce_out, dim3(128), dim3(256), 0, stream,
                               part, bb, (float*)d_out, ksplit);
        }
    }
}

// Round 4
// 580.340 us; speedup vs baseline: 2.9624x; 1.1768x over previous
//
#include <hip/hip_runtime.h>
#include <hip/hip_bf16.h>

#define E_ 128
#define NSAMP 2048

typedef __attribute__((ext_vector_type(8))) short short8;
typedef __attribute__((ext_vector_type(4))) float floatx4;

__device__ __forceinline__ ushort f2b(float f) {
    union { __hip_bfloat16 h; ushort u; } cv;
    cv.h = __float2bfloat16(f);
    return cv.u;
}

__device__ __forceinline__ void gload_lds16(const ushort* g, ushort* l) {
    __builtin_amdgcn_global_load_lds(
        (const __attribute__((address_space(1))) void*)g,
        (__attribute__((address_space(3))) void*)l, 16, 0, 0);
}

// -------------------- h = ReLU(ids @ l1W^T + l1b), fp32 --------------------
__global__ void hyper_h(const float* __restrict__ input, const float* __restrict__ l1W,
                        const float* __restrict__ l1b, float* __restrict__ h)
{
    int b = blockIdx.x / 5;
    int o = (blockIdx.x % 5) * 256 + threadIdx.x;
    const float* ids = input + (size_t)b * 192 + 176;
    const float* w = l1W + (size_t)o * 16;
    float a = l1b[o];
#pragma unroll
    for (int i = 0; i < 16; i += 4) {
        float4 wv = *(const float4*)(w + i);
        a += ids[i] * wv.x + ids[i + 1] * wv.y + ids[i + 2] * wv.z + ids[i + 3] * wv.w;
    }
    h[(size_t)b * 1280 + o] = fmaxf(a, 0.f);
}

// -------------------- xT0[s][b] = input[b][s]  (s < 176), fp32 --------------------
__global__ void x0_t(const float* __restrict__ input, float* __restrict__ xT0)
{
    int idx = blockIdx.x * 256 + threadIdx.x;   // < 176*2048
    int s = idx >> 11, b = idx & 2047;
    xT0[idx] = input[(size_t)b * 192 + s];
}

// -------------------- fp32 -> bf16 convert (wW bulk) --------------------
__global__ void cvt_bf16(const float* __restrict__ src, ushort* __restrict__ dst, int n)
{
    int i = (blockIdx.x * 256 + threadIdx.x) * 8;
    if (i >= n) return;
    float4 a = *(const float4*)(src + i);
    float4 b = *(const float4*)(src + i + 4);
    union { ushort o[8]; uint4 v; } u;
    u.o[0] = f2b(a.x); u.o[1] = f2b(a.y); u.o[2] = f2b(a.z); u.o[3] = f2b(a.w);
    u.o[4] = f2b(b.x); u.o[5] = f2b(b.y); u.o[6] = f2b(b.z); u.o[7] = f2b(b.w);
    *(uint4*)(dst + i) = u.v;
}

// -------------------- build 3 virtual B-slices: [S]=bW rows, [S+1..S+2]=wb^T chunks --------
__global__ void cvt_bias(const float* __restrict__ bW, const float* __restrict__ wb,
                         ushort* __restrict__ dst, int S, int M)
{
    int idx = blockIdx.x * 256 + threadIdx.x;   // < 3*M*E_
    int slice = idx / (M * E_);
    int rem = idx - slice * (M * E_);
    int m = rem / E_, e = rem - m * E_;
    ushort v;
    if (slice == 0) {
        v = f2b(bW[(size_t)m * E_ + e]);
    } else {
        int s = (slice - 1) * 128 + e;
        v = (s < S) ? f2b(wb[(size_t)s * M + m]) : (ushort)0;
    }
    dst[(size_t)(S + slice) * M * E_ + rem] = v;
}

// ==================== big-layer GEMM (M=256): async LDS staging ====================
// BM=BN=128, 4 waves (2x2), BK=64 per phase. As/Bs unpadded [128][64] shorts with
// XOR-swizzled 16B groups: group g stored at g' = g ^ (row&7)  -> conflict-free
// ds_write_b128 / ds_read_b128, and lane-contiguous slots for global_load_lds.
__global__ __launch_bounds__(256, 2) void gemm_big(
    const ushort* __restrict__ wWb, const float* __restrict__ h,
    const float* __restrict__ xT, float* __restrict__ partial,
    int S, int iw, int ksplit, int btiles, int ntiles)
{
    __shared__ ushort As[128 * 64];
    __shared__ ushort Bs[128 * 64];

    const int tid = threadIdx.x;
    const int bt = blockIdx.x % btiles;
    const int nt = (blockIdx.x / btiles) % ntiles;
    const int ks = blockIdx.x / (btiles * ntiles);
    const int b0 = bt * 128;
    const int m0 = nt * 128;
    const int total_s = S + 3;
    const int base = total_s / ksplit;
    const int rem = total_s - base * ksplit;
    const int s0 = ks * base + min(ks, rem);
    const int s1 = s0 + base + (ks < rem ? 1 : 0);

    const int lane = tid & 63;
    const int wave = tid >> 6;
    const int quad = lane >> 4;
    const int lr = lane & 15;
    const int wm0 = (wave >> 1) * 64;
    const int wn0 = (wave & 1) * 64;

    const int tb = tid >> 3;            // A-gen row (0..31), +32*k2
    const int teg = tid & 7;            // A-gen e-group
    const int aswz = (teg ^ (tb & 7)) * 8;   // swizzled A slot (shorts)

    const int brow = lane >> 3;         // B-DMA local row (0..7)
    const int bgg = (lane & 7) ^ brow;  // global e-group for this lane's slot

    // preload h chunk (iw) fp32: hreg[k2][p][j] = h[b0+tb+32k2][iw*128 + p*64 + teg*8 + j]
    float hreg[4][2][8];
#pragma unroll
    for (int k2 = 0; k2 < 4; ++k2) {
#pragma unroll
        for (int p = 0; p < 2; ++p) {
            const float* src = h + (size_t)(b0 + tb + 32 * k2) * 1280 + (size_t)iw * E_ + p * 64 + teg * 8;
            float4 v0 = *(const float4*)(src);
            float4 v1 = *(const float4*)(src + 4);
            hreg[k2][p][0] = v0.x; hreg[k2][p][1] = v0.y; hreg[k2][p][2] = v0.z; hreg[k2][p][3] = v0.w;
            hreg[k2][p][4] = v1.x; hreg[k2][p][5] = v1.y; hreg[k2][p][6] = v1.z; hreg[k2][p][7] = v1.w;
        }
    }

    floatx4 acc[4][4];
#pragma unroll
    for (int i = 0; i < 4; ++i)
#pragma unroll
        for (int j = 0; j < 4; ++j)
            acc[i][j] = (floatx4){0.f, 0.f, 0.f, 0.f};

    for (int s = s0; s < s1; ++s) {
        float xv[4];
        if (s < S) {
#pragma unroll
            for (int k2 = 0; k2 < 4; ++k2)
                xv[k2] = xT[(size_t)s * NSAMP + b0 + tb + 32 * k2];
        }

#pragma unroll
        for (int p = 0; p < 2; ++p) {
            __syncthreads();   // previous phase's frag reads complete

            // ---- B: async global->LDS DMA (issued first; flight hides behind A-gen) ----
#pragma unroll
            for (int t = 0; t < 4; ++t) {
                int rloc = wave * 32 + t * 8;
                const ushort* gp = wWb + ((size_t)s * 256 + m0 + rloc + brow) * E_ + p * 64 + bgg * 8;
                ushort* lp = &Bs[(size_t)rloc * 64] + lane * 8;
                gload_lds16(gp, lp);
            }

            // ---- A: generate and stage via LDS (swizzled slots) ----
            if (s < S) {
#pragma unroll
                for (int k2 = 0; k2 < 4; ++k2) {
                    union { ushort o[8]; uint4 v; } u;
#pragma unroll
                    for (int j = 0; j < 8; ++j) u.o[j] = f2b(xv[k2] * hreg[k2][p][j]);
                    *(uint4*)&As[(size_t)(tb + 32 * k2) * 64 + aswz] = u.v;
                }
            } else if (s == S) {
#pragma unroll
                for (int k2 = 0; k2 < 4; ++k2) {
                    const float* src = h + (size_t)(b0 + tb + 32 * k2) * 1280
                                         + (size_t)(iw + 1) * E_ + p * 64 + teg * 8;
                    float4 v0 = *(const float4*)(src);
                    float4 v1 = *(const float4*)(src + 4);
                    union { ushort o[8]; uint4 v; } u;
                    u.o[0] = f2b(v0.x); u.o[1] = f2b(v0.y); u.o[2] = f2b(v0.z); u.o[3] = f2b(v0.w);
                    u.o[4] = f2b(v1.x); u.o[5] = f2b(v1.y); u.o[6] = f2b(v1.z); u.o[7] = f2b(v1.w);
                    *(uint4*)&As[(size_t)(tb + 32 * k2) * 64 + aswz] = u.v;
                }
            } else {
                int j0 = (s - S - 1) * 128 + p * 64 + teg * 8;
#pragma unroll
                for (int k2 = 0; k2 < 4; ++k2) {
                    int b = b0 + tb + 32 * k2;
                    union { ushort o[8]; uint4 v; } u;
#pragma unroll
                    for (int jj = 0; jj < 8; ++jj) {
                        int sp = j0 + jj;
                        u.o[jj] = (sp < S) ? f2b(xT[(size_t)sp * NSAMP + b]) : (ushort)0;
                    }
                    *(uint4*)&As[(size_t)(tb + 32 * k2) * 64 + aswz] = u.v;
                }
            }

            __syncthreads();   // staging (incl. DMA via vmcnt drain) visible

            // ---- MFMA on this phase ----
#pragma unroll
            for (int kk = 0; kk < 2; ++kk) {
                const int swz = ((kk * 4 + quad) ^ (lr & 7)) * 8;
                short8 af[4], bfr[4];
#pragma unroll
                for (int i = 0; i < 4; ++i)
                    af[i] = *(const short8*)&As[(size_t)(wm0 + i * 16 + lr) * 64 + swz];
#pragma unroll
                for (int j = 0; j < 4; ++j)
                    bfr[j] = *(const short8*)&Bs[(size_t)(wn0 + j * 16 + lr) * 64 + swz];
#pragma unroll
                for (int i = 0; i < 4; ++i)
#pragma unroll
                    for (int j = 0; j < 4; ++j)
                        acc[i][j] = __builtin_amdgcn_mfma_f32_16x16x32_bf16(af[i], bfr[j], acc[i][j], 0, 0, 0);
            }
        }
    }

    // epilogue: C/D layout col=lane&15, row=quad*4+r
    float* dst = partial + (size_t)ks * NSAMP * 256;
#pragma unroll
    for (int i = 0; i < 4; ++i)
#pragma unroll
        for (int j = 0; j < 4; ++j)
#pragma unroll
            for (int r = 0; r < 4; ++r) {
                int row = wm0 + i * 16 + quad * 4 + r;
                int col = wn0 + j * 16 + lr;
                dst[(size_t)(b0 + row) * 256 + m0 + col] = acc[i][j][r];
            }
}

// ==================== small-layer GEMM (M=16) — previous structure ====================
template<int BM, int BN, int WROWS, int WCOLS>
__global__ __launch_bounds__(256, 2) void gemm_k(
    const ushort* __restrict__ wWb, const float* __restrict__ h,
    const float* __restrict__ xT, float* __restrict__ partial,
    int S, int M, int iw, int ksplit, int btiles, int ntiles)
{
    constexpr int SM = BM / WROWS / 16;
    constexpr int SN = BN / WCOLS / 16;
    constexpr int ASLOTS = BM * 8 / 256;
    constexpr int LDA = 72;

    __shared__ ushort As[BM][LDA];
    __shared__ ushort Bs[BN][LDA];

    const int tid = threadIdx.x;
    const int bt = blockIdx.x % btiles;
    const int nt = (blockIdx.x / btiles) % ntiles;
    const int ks = blockIdx.x / (btiles * ntiles);
    const int b0 = bt * BM;
    const int m0 = nt * BN;
    const int total_s = S + 3;
    const int base = total_s / ksplit;
    const int rem = total_s - base * ksplit;
    const int s0 = ks * base + min(ks, rem);
    const int s1 = s0 + base + (ks < rem ? 1 : 0);

    const int lane = tid & 63;
    const int wave = tid >> 6;
    const int quad = lane >> 4;
    const int lr = lane & 15;
    const int wm0 = (wave / WCOLS) * (BM / WROWS);
    const int wn0 = (wave % WCOLS) * (BN / WCOLS);

    const int tb = tid >> 3;
    const int teg = tid & 7;

    float hreg[ASLOTS][2][8];
#pragma unroll
    for (int k2 = 0; k2 < ASLOTS; ++k2) {
        int b = tb + 32 * k2;
#pragma unroll
        for (int p = 0; p < 2; ++p) {
            const float* src = h + (size_t)(b0 + b) * 1280 + (size_t)iw * E_ + p * 64 + teg * 8;
            float4 v0 = *(const float4*)(src);
            float4 v1 = *(const float4*)(src + 4);
            hreg[k2][p][0] = v0.x; hreg[k2][p][1] = v0.y; hreg[k2][p][2] = v0.z; hreg[k2][p][3] = v0.w;
            hreg[k2][p][4] = v1.x; hreg[k2][p][5] = v1.y; hreg[k2][p][6] = v1.z; hreg[k2][p][7] = v1.w;
        }
    }

    floatx4 acc[SM][SN];
#pragma unroll
    for (int i = 0; i < SM; ++i)
#pragma unroll
        for (int j = 0; j < SN; ++j)
            acc[i][j] = (floatx4){0.f, 0.f, 0.f, 0.f};

    for (int s = s0; s < s1; ++s) {
        float xv[ASLOTS];
        if (s < S) {
#pragma unroll
            for (int k2 = 0; k2 < ASLOTS; ++k2)
                xv[k2] = xT[(size_t)s * NSAMP + b0 + tb + 32 * k2];
        }

#pragma unroll
        for (int p = 0; p < 2; ++p) {
            if (s < S) {
#pragma unroll
                for (int k2 = 0; k2 < ASLOTS; ++k2) {
                    union { ushort o[8]; uint4 v; } u;
#pragma unroll
                    for (int j = 0; j < 8; ++j) u.o[j] = f2b(xv[k2] * hreg[k2][p][j]);
                    *(uint4*)&As[tb + 32 * k2][teg * 8] = u.v;
                }
            } else if (s == S) {
#pragma unroll
                for (int k2 = 0; k2 < ASLOTS; ++k2) {
                    const float* src = h + (size_t)(b0 + tb + 32 * k2) * 1280
                                         + (size_t)(iw + 1) * E_ + p * 64 + teg * 8;
                    float4 v0 = *(const float4*)(src);
                    float4 v1 = *(const float4*)(src + 4);
                    union { ushort o[8]; uint4 v; } u;
                    u.o[0] = f2b(v0.x); u.o[1] = f2b(v0.y); u.o[2] = f2b(v0.z); u.o[3] = f2b(v0.w);
                    u.o[4] = f2b(v1.x); u.o[5] = f2b(v1.y); u.o[6] = f2b(v1.z); u.o[7] = f2b(v1.w);
                    *(uint4*)&As[tb + 32 * k2][teg * 8] = u.v;
                }
            } else {
                int j0 = (s - S - 1) * 128 + p * 64 + teg * 8;
#pragma unroll
                for (int k2 = 0; k2 < ASLOTS; ++k2) {
                    int b = b0 + tb + 32 * k2;
                    union { ushort o[8]; uint4 v; } u;
#pragma unroll
                    for (int jj = 0; jj < 8; ++jj) {
                        int sp = j0 + jj;
                        u.o[jj] = (sp < S) ? f2b(xT[(size_t)sp * NSAMP + b]) : (ushort)0;
                    }
                    *(uint4*)&As[tb + 32 * k2][teg * 8] = u.v;
                }
            }
#pragma unroll
            for (int slot = tid; slot < BN * 8; slot += 256) {
                int m = slot >> 3, eg2 = slot & 7;
                *(uint4*)&Bs[m][eg2 * 8] =
                    *(const uint4*)(wWb + ((size_t)s * M + m0 + m) * E_ + p * 64 + eg2 * 8);
            }
            __syncthreads();
#pragma unroll
            for (int kk = 0; kk < 2; ++kk) {
                short8 af[SM], bfr[SN];
#pragma unroll
                for (int i = 0; i < SM; ++i)
                    af[i] = *(const short8*)&As[wm0 + i * 16 + lr][kk * 32 + quad * 8];
#pragma unroll
                for (int j = 0; j < SN; ++j)
                    bfr[j] = *(const short8*)&Bs[wn0 + j * 16 + lr][kk * 32 + quad * 8];
#pragma unroll
                for (int i = 0; i < SM; ++i)
#pragma unroll
                    for (int j = 0; j < SN; ++j)
                        acc[i][j] = __builtin_amdgcn_mfma_f32_16x16x32_bf16(af[i], bfr[j], acc[i][j], 0, 0, 0);
            }
            __syncthreads();
        }
    }

    float* dst = partial + (size_t)ks * NSAMP * M;
#pragma unroll
    for (int i = 0; i < SM; ++i)
#pragma unroll
        for (int j = 0; j < SN; ++j)
#pragma unroll
            for (int r = 0; r < 4; ++r) {
                int row = wm0 + i * 16 + quad * 4 + r;
                int col = wn0 + j * 16 + lr;
                dst[(size_t)(b0 + row) * M + m0 + col] = acc[i][j][r];
            }
}

// -------------------- reduce partials + bb (+ReLU), emit xT fp32 for next layer --------------
__global__ void reduce_mid(const float* __restrict__ partial, const float* __restrict__ bb,
                           float* __restrict__ xTn, int KS, int relu)
{
    __shared__ float t[32][33];
    const int b0 = (blockIdx.x >> 3) * 32;
    const int m0 = (blockIdx.x & 7) * 32;
    const int mo = threadIdx.x & 31;
    const int bs0 = threadIdx.x >> 5;   // 0..7
    const float bv = bb[m0 + mo];
#pragma unroll
    for (int r = 0; r < 4; ++r) {
        const int bs = bs0 + 8 * r;
        const size_t off = (size_t)(b0 + bs) * 256 + m0 + mo;
        float a0 = 0.f, a1 = 0.f, a2 = 0.f, a3 = 0.f;
#pragma unroll
        for (int k = 0; k < 16; k += 4) {
            a0 += partial[(size_t)(k + 0) * (NSAMP * 256) + off];
            a1 += partial[(size_t)(k + 1) * (NSAMP * 256) + off];
            a2 += partial[(size_t)(k + 2) * (NSAMP * 256) + off];
            a3 += partial[(size_t)(k + 3) * (NSAMP * 256) + off];
        }
        float a = (a0 + a1) + (a2 + a3) + bv;
        if (relu) a = fmaxf(a, 0.f);
        t[bs][mo] = a;
    }
    __syncthreads();
    const int bo = threadIdx.x & 31;
    const int ms0 = threadIdx.x >> 5;
#pragma unroll
    for (int r = 0; r < 4; ++r) {
        const int ms = ms0 + 8 * r;
        xTn[(size_t)(m0 + ms) * NSAMP + b0 + bo] = t[bo][ms];
    }
}

// -------------------- final layer reduce -> d_out (fp32, ReLU) --------------------
__global__ void reduce_out(const float* __restrict__ partial, const float* __restrict__ bb,
                           float* __restrict__ out, int KS)
{
    int idx = blockIdx.x * 256 + threadIdx.x;   // < 2048*16
    float a0 = 0.f, a1 = 0.f, a2 = 0.f, a3 = 0.f;
#pragma unroll
    for (int k = 0; k < 32; k += 4) {
        a0 += partial[(size_t)(k + 0) * (NSAMP * 16) + idx];
        a1 += partial[(size_t)(k + 1) * (NSAMP * 16) + idx];
        a2 += partial[(size_t)(k + 2) * (NSAMP * 16) + idx];
        a3 += partial[(size_t)(k + 3) * (NSAMP * 16) + idx];
    }
    out[idx] = fmaxf((a0 + a1) + (a2 + a3) + bb[idx & 15], 0.f);
}

extern "C" void kernel_launch(void* const* d_in, const int* in_sizes, int n_in,
                              void* d_out, int out_size, void* d_ws, size_t ws_size,
                              hipStream_t stream)
{
    const float* input = (const float*)d_in[0];
    const float* l1W   = (const float*)d_in[1];
    const float* l1b   = (const float*)d_in[2];

    char* ws = (char*)d_ws;
    // layout (bytes): wWb 16.98M | h 10.49M | xT0 2M | xT1 2M | partial 33.55M = 65.2MB
    ushort* wWb = (ushort*)(ws + 0);
    float* h    = (float*)(ws + 16975872);
    float* xT0  = (float*)(ws + 27461632);
    float* xT1  = (float*)(ws + 29558784);
    float* part = (float*)(ws + 31655936);

    hipLaunchKernelGGL(hyper_h, dim3(2048 * 5), dim3(256), 0, stream, input, l1W, l1b, h);
    hipLaunchKernelGGL(x0_t, dim3(176 * 2048 / 256), dim3(256), 0, stream, input, xT0);

    const int S_[5] = {176, 256, 256, 256, 256};
    const int M_[5] = {256, 256, 256, 256, 16};
    float* xt[2] = {xT0, xT1};

    for (int i = 0; i < 5; ++i) {
        const float* wW = (const float*)d_in[3 + 4 * i];
        const float* wb = (const float*)d_in[4 + 4 * i];
        const float* bW = (const float*)d_in[5 + 4 * i];
        const float* bb = (const float*)d_in[6 + 4 * i];
        float* xin = xt[i & 1];
        int n = S_[i] * M_[i] * E_;
        hipLaunchKernelGGL(cvt_bf16, dim3(n / 2048), dim3(256), 0, stream, wW, wWb, n);
        hipLaunchKernelGGL(cvt_bias, dim3(3 * M_[i] * E_ / 256), dim3(256), 0, stream,
                           bW, wb, wWb, S_[i], M_[i]);

        if (M_[i] == 256) {
            const int btiles = 16, ntiles = 2, ksplit = 16;
            hipLaunchKernelGGL(gemm_big, dim3(btiles * ntiles * ksplit), dim3(256), 0, stream,
                               wWb, h, xin, part, S_[i], 2 * i, ksplit, btiles, ntiles);
            hipLaunchKernelGGL(reduce_mid, dim3(512), dim3(256), 0, stream,
                               part, bb, xt[(i + 1) & 1], ksplit, (i < 3) ? 1 : 0);
        } else {
            const int btiles = 8, ntiles = 1, ksplit = 32;
            hipLaunchKernelGGL((gemm_k<256, 16, 4, 1>), dim3(btiles * ntiles * ksplit), dim3(256), 0, stream,
                               wWb, h, xin, part, S_[i], 16, 2 * i, ksplit, btiles, ntiles);
            hipLaunchKernelGGL(reduce_out, dim3(128), dim3(256), 0, stream,
                               part, bb, (float*)d_out, ksplit);
        }
    }
}